// Round 1
// baseline (219.595 us; speedup 1.0000x reference)
//
#include <hip/hip_runtime.h>
#include <stdint.h>

#define LOG2E 1.4426950408889634f

typedef __attribute__((ext_vector_type(8))) __bf16 bf16x8;
typedef __attribute__((ext_vector_type(4))) __bf16 bf16x4;
typedef __attribute__((ext_vector_type(4))) float f32x4;

__device__ inline void gll16(const void* g, void* l) {
  __builtin_amdgcn_global_load_lds(
      (const __attribute__((address_space(1))) void*)g,
      (__attribute__((address_space(3))) void*)l, 16, 0, 0);
}

// ---------------- fp32 -> bf16 conversion ----------------
__global__ __launch_bounds__(256) void cvt_kernel(const float* __restrict__ src,
                                                  __bf16* __restrict__ dst, int n4) {
  int i = blockIdx.x * 256 + threadIdx.x;
  if (i < n4) {
    float4 v = ((const float4*)src)[i];
    bf16x4 o;
    o[0] = (__bf16)v.x; o[1] = (__bf16)v.y; o[2] = (__bf16)v.z; o[3] = (__bf16)v.w;
    *(bf16x4*)&dst[(size_t)i * 4] = o;
  }
}

// ---------------- GEMM: C = A[M,K] * Bt[N,K]^T, K=1024 ----------------
// EPI 0: write bf16 to [b,h,s,d] (Q/K projection; m = b*2048+s, n = h*64+d)
// EPI 1: write bf16 to [b,h,d,s] (V^T; rows of C are o = h*64+d, cols are m)
// EPI 2: write fp32 row-major [M,N] (final output)
template<int EPI>
__global__ __launch_bounds__(256, 2) void gemm_bt(const __bf16* __restrict__ A,
                                                  const __bf16* __restrict__ Bt,
                                                  void* __restrict__ Cp,
                                                  int M, int N) {
  constexpr int K = 1024;
  __shared__ __align__(16) __bf16 lta[128 * 32];
  __shared__ __align__(16) __bf16 ltb[128 * 32];
  const int tid = threadIdx.x;
  const int w = tid >> 6, l = tid & 63;
  const int lg = l >> 4, lr = l & 15;
  const int m0 = blockIdx.x * 128, n0 = blockIdx.y * 128;
  const int wm = (w >> 1) * 64, wn = (w & 1) * 64;
  f32x4 acc[4][4] = {};
  const int srow = w * 16 + (l >> 2);
  const int scol = (l & 3) * 8;
  const __bf16* ga = A + (size_t)(m0 + srow) * K + scol;
  const __bf16* gb = Bt + (size_t)(n0 + srow) * K + scol;
  __bf16* la = &lta[(size_t)w * 16 * 32];
  __bf16* lb = &ltb[(size_t)w * 16 * 32];
  for (int k0 = 0; k0 < K; k0 += 32) {
    __syncthreads();
    gll16(ga + k0, la);
    gll16(ga + 64 * K + k0, la + 64 * 32);
    gll16(gb + k0, lb);
    gll16(gb + 64 * K + k0, lb + 64 * 32);
    __syncthreads();
    bf16x8 af[4], bfr[4];
#pragma unroll
    for (int i = 0; i < 4; ++i) {
      af[i]  = *(const bf16x8*)&lta[(wm + i * 16 + lr) * 32 + lg * 8];
      bfr[i] = *(const bf16x8*)&ltb[(wn + i * 16 + lr) * 32 + lg * 8];
    }
#pragma unroll
    for (int i = 0; i < 4; ++i)
#pragma unroll
      for (int j = 0; j < 4; ++j)
        acc[i][j] = __builtin_amdgcn_mfma_f32_16x16x32_bf16(af[i], bfr[j], acc[i][j], 0, 0, 0);
  }
#pragma unroll
  for (int i = 0; i < 4; ++i)
#pragma unroll
    for (int j = 0; j < 4; ++j)
#pragma unroll
      for (int r = 0; r < 4; ++r) {
        int gm = m0 + wm + i * 16 + lg * 4 + r;
        int gn = n0 + wn + j * 16 + lr;
        float v = acc[i][j][r];
        if constexpr (EPI == 0) {
          int bb = gm >> 11, s = gm & 2047, hh = gn >> 6, d = gn & 63;
          ((__bf16*)Cp)[(((size_t)bb * 16 + hh) * 2048 + s) * 64 + d] = (__bf16)v;
        } else if constexpr (EPI == 1) {
          int bb = gn >> 11, s = gn & 2047, hh = gm >> 6, d = gm & 63;
          ((__bf16*)Cp)[(((size_t)bb * 16 + hh) * 64 + d) * 2048 + s] = (__bf16)v;
        } else {
          ((float*)Cp)[(size_t)gm * N + gn] = v;
        }
      }
}

// ---------------- attention + memory retrieval ----------------
// grid: (16 q-tiles, 32 bh), 256 threads (4 waves). Wave w owns q rows
// q0 + w*32 .. +31. Flash over 128-wide KV tiles (causal).
#define KP 72    // K-tile padded cols   (d: 64 -> 72)   row stride 144B (16-mult)
#define VP 136   // V^T-tile padded cols (sk: 128 -> 136) row stride 272B
#define PP 136   // P-tile padded cols
#define MTP 72   // memory^T padded cols

__global__ __launch_bounds__(256, 2) void attn_kernel(
    const __bf16* __restrict__ qb,    // [32][2048][64]
    const __bf16* __restrict__ kb,    // [32][2048][64]
    const __bf16* __restrict__ vtb,   // [32][64][2048]
    const float* __restrict__ memory, // [16][64][64]
    const float* __restrict__ memnorm,// [16][64]
    const float* __restrict__ beta,   // [16]
    __bf16* __restrict__ comb)        // [2][2048][16][64] == [4096][1024]
{
  __shared__ __align__(16) __bf16 kt[128 * KP];     // 18432 B
  __shared__ __align__(16) __bf16 vt[64 * VP];      // 17408 B
  __shared__ __align__(16) __bf16 pt[4 * 32 * PP];  // 34816 B (also hosts MT: 80*72)

  const int tid = threadIdx.x;
  const int w = tid >> 6, l = tid & 63;
  const int lg = l >> 4, lr = l & 15;
  const int qt = blockIdx.x, bh = blockIdx.y;
  const int hh = bh & 15, b = bh >> 4;
  const int q0 = qt * 128;
  const int wq0 = q0 + w * 32;

  // ---- hoist Q fragments (A-layout: row=lr, k = kk*32 + lg*8 + j) ----
  bf16x8 qf[2][2];
#pragma unroll
  for (int mf = 0; mf < 2; ++mf)
#pragma unroll
    for (int kk = 0; kk < 2; ++kk)
      qf[mf][kk] = *(const bf16x8*)(qb + ((size_t)bh * 2048 + wq0 + mf * 16 + lr) * 64 + kk * 32 + lg * 8);

  // ---- flash state ----
  float mrun[2][4], lsum[2][4];
  f32x4 ap[2][4] = {};
#pragma unroll
  for (int mf = 0; mf < 2; ++mf)
#pragma unroll
    for (int r = 0; r < 4; ++r) { mrun[mf][r] = -1e30f; lsum[mf][r] = 0.f; }

  for (int t = 0; t <= qt; ++t) {
    const int kv0 = t * 128;
    __syncthreads();
    // stage K tile [128][64] -> kt[128][KP], V^T tile [64][128] -> vt[64][VP]
#pragma unroll
    for (int is = 0; is < 4; ++is) {
      int i16 = is * 256 + tid;                 // 0..1023
      int sk = i16 >> 3, d8 = (i16 & 7) * 8;    // K tile: 8 chunks/row
      *(bf16x8*)&kt[sk * KP + d8] =
          *(const bf16x8*)(kb + ((size_t)bh * 2048 + kv0 + sk) * 64 + d8);
      int d = i16 >> 4, sk8 = (i16 & 15) * 8;   // V^T tile: 16 chunks/row
      *(bf16x8*)&vt[d * VP + sk8] =
          *(const bf16x8*)(vtb + ((size_t)bh * 64 + d) * 2048 + kv0 + sk8);
    }
    __syncthreads();

    // ---- QK^T ----
    f32x4 sc[2][8] = {};
#pragma unroll
    for (int kk = 0; kk < 2; ++kk)
#pragma unroll
      for (int nf = 0; nf < 8; ++nf) {
        bf16x8 bb = *(const bf16x8*)&kt[(nf * 16 + lr) * KP + kk * 32 + lg * 8];
#pragma unroll
        for (int mf = 0; mf < 2; ++mf)
          sc[mf][nf] = __builtin_amdgcn_mfma_f32_16x16x32_bf16(qf[mf][kk], bb, sc[mf][nf], 0, 0, 0);
      }

    // ---- scale + causal mask + row max ----
    const bool diag = (kv0 + 127 > wq0);
    float mnew[2][4];
#pragma unroll
    for (int mf = 0; mf < 2; ++mf)
#pragma unroll
      for (int r = 0; r < 4; ++r) mnew[mf][r] = -1e30f;
#pragma unroll
    for (int mf = 0; mf < 2; ++mf)
#pragma unroll
      for (int nf = 0; nf < 8; ++nf)
#pragma unroll
        for (int r = 0; r < 4; ++r) {
          float v = sc[mf][nf][r] * 0.125f;
          if (diag) {
            int row = wq0 + mf * 16 + lg * 4 + r;
            int col = kv0 + nf * 16 + lr;
            if (col > row) v = -1e30f;
          }
          sc[mf][nf][r] = v;
          mnew[mf][r] = fmaxf(mnew[mf][r], v);
        }
#pragma unroll
    for (int msk = 1; msk < 16; msk <<= 1)
#pragma unroll
      for (int mf = 0; mf < 2; ++mf)
#pragma unroll
        for (int r = 0; r < 4; ++r)
          mnew[mf][r] = fmaxf(mnew[mf][r], __shfl_xor(mnew[mf][r], msk, 64));

    // ---- rescale running state ----
    float rs[2][4];
#pragma unroll
    for (int mf = 0; mf < 2; ++mf)
#pragma unroll
      for (int r = 0; r < 4; ++r) {
        float mo = mrun[mf][r];
        float mn = fmaxf(mo, mnew[mf][r]);
        mrun[mf][r] = mn;
        float scl = __builtin_amdgcn_exp2f((mo - mn) * LOG2E);
        lsum[mf][r] *= scl;
        rs[mf][r] = 0.f;
#pragma unroll
        for (int nf = 0; nf < 4; ++nf) ap[mf][nf][r] *= scl;
      }

    // ---- P = exp(S - m), row-sum, stash to LDS (D-layout -> A-layout) ----
#pragma unroll
    for (int mf = 0; mf < 2; ++mf)
#pragma unroll
      for (int nf = 0; nf < 8; ++nf)
#pragma unroll
        for (int r = 0; r < 4; ++r) {
          float p = __builtin_amdgcn_exp2f((sc[mf][nf][r] - mrun[mf][r]) * LOG2E);
          rs[mf][r] += p;
          pt[(size_t)w * 32 * PP + (mf * 16 + lg * 4 + r) * PP + nf * 16 + lr] = (__bf16)p;
        }
#pragma unroll
    for (int msk = 1; msk < 16; msk <<= 1)
#pragma unroll
      for (int mf = 0; mf < 2; ++mf)
#pragma unroll
        for (int r = 0; r < 4; ++r)
          rs[mf][r] += __shfl_xor(rs[mf][r], msk, 64);
#pragma unroll
    for (int mf = 0; mf < 2; ++mf)
#pragma unroll
      for (int r = 0; r < 4; ++r) lsum[mf][r] += rs[mf][r];

    // ---- PV accumulate (A = P from LDS, B = V^T from LDS) ----
#pragma unroll
    for (int kk = 0; kk < 4; ++kk) {
      bf16x8 pa[2];
#pragma unroll
      for (int mf = 0; mf < 2; ++mf)
        pa[mf] = *(const bf16x8*)&pt[(size_t)w * 32 * PP + (mf * 16 + lr) * PP + kk * 32 + lg * 8];
#pragma unroll
      for (int nf = 0; nf < 4; ++nf) {
        bf16x8 bb = *(const bf16x8*)&vt[(nf * 16 + lr) * VP + kk * 32 + lg * 8];
#pragma unroll
        for (int mf = 0; mf < 2; ++mf)
          ap[mf][nf] = __builtin_amdgcn_mfma_f32_16x16x32_bf16(pa[mf], bb, ap[mf][nf], 0, 0, 0);
      }
    }
  }

  // ---- memory retrieval: sigma(Q) @ [M^T | mn replicated] via MFMA ----
  __syncthreads();  // all waves done with pt (P) reads
  __bf16* mt = pt;  // reuse pt region for memory^T [80][MTP]
  for (int i = tid; i < 64 * 64; i += 256) {
    int d = i >> 6, e = i & 63;
    mt[e * MTP + d] = (__bf16)memory[((size_t)hh * 64 + d) * 64 + e];
  }
  for (int i = tid; i < 16 * 64; i += 256) {
    int e = 64 + (i >> 6), d = i & 63;   // rows 64..79 all hold memnorm -> every
    mt[e * MTP + d] = (__bf16)memnorm[hh * 64 + d];  // lane gets norm in col l&15
  }
  __syncthreads();

  bf16x8 sf[2][2];
#pragma unroll
  for (int mf = 0; mf < 2; ++mf)
#pragma unroll
    for (int kk = 0; kk < 2; ++kk) {
      bf16x8 q = qf[mf][kk], s;
#pragma unroll
      for (int j = 0; j < 8; ++j) {
        float x = (float)q[j];
        float sg = x > 0.f ? x + 1.f : __builtin_amdgcn_exp2f(x * LOG2E);
        s[j] = (__bf16)sg;
      }
      sf[mf][kk] = s;
    }

  f32x4 am[2][5] = {};
#pragma unroll
  for (int kk = 0; kk < 2; ++kk)
#pragma unroll
    for (int nf = 0; nf < 5; ++nf) {
      bf16x8 bb = *(const bf16x8*)&mt[(nf * 16 + lr) * MTP + kk * 32 + lg * 8];
#pragma unroll
      for (int mf = 0; mf < 2; ++mf)
        am[mf][nf] = __builtin_amdgcn_mfma_f32_16x16x32_bf16(sf[mf][kk], bb, am[mf][nf], 0, 0, 0);
    }

  // ---- combine + write ----
  float gate = 1.f / (1.f + __builtin_amdgcn_exp2f(-beta[hh] * LOG2E));
  float og = 1.f - gate;
#pragma unroll
  for (int mf = 0; mf < 2; ++mf)
#pragma unroll
    for (int r = 0; r < 4; ++r) {
      int row = wq0 + mf * 16 + lg * 4 + r;
      float linv = __builtin_amdgcn_rcpf(lsum[mf][r]);
      float nrm = fmaxf(am[mf][4][r], 1e-6f);
      float ninv = __builtin_amdgcn_rcpf(nrm);
      size_t base = ((size_t)b * 2048 + row) * 1024 + hh * 64;
#pragma unroll
      for (int nf = 0; nf < 4; ++nf) {
        float al = ap[mf][nf][r] * linv;
        float amv = am[mf][nf][r] * ninv;
        comb[base + nf * 16 + lr] = (__bf16)(gate * amv + og * al);
      }
    }
}

// ---------------- launch ----------------
extern "C" void kernel_launch(void* const* d_in, const int* in_sizes, int n_in,
                              void* d_out, int out_size, void* d_ws, size_t ws_size,
                              hipStream_t stream) {
  const float* hs      = (const float*)d_in[0];
  const float* wq      = (const float*)d_in[1];
  const float* wk      = (const float*)d_in[2];
  const float* wv      = (const float*)d_in[3];
  const float* wo      = (const float*)d_in[4];
  const float* beta    = (const float*)d_in[5];
  const float* memory  = (const float*)d_in[6];
  const float* memnorm = (const float*)d_in[7];
  float* out = (float*)d_out;

  char* ws = (char*)d_ws;
  __bf16* hsb  = (__bf16*)(ws);                        // 8 MB  [4096][1024]
  __bf16* wqb  = (__bf16*)(ws + ((size_t)8  << 20));   // 2 MB
  __bf16* wkb  = (__bf16*)(ws + ((size_t)10 << 20));   // 2 MB
  __bf16* wvb  = (__bf16*)(ws + ((size_t)12 << 20));   // 2 MB
  __bf16* wob  = (__bf16*)(ws + ((size_t)14 << 20));   // 2 MB
  __bf16* qbuf = (__bf16*)(ws + ((size_t)16 << 20));   // 8 MB  [32][2048][64]
  __bf16* kbuf = (__bf16*)(ws + ((size_t)24 << 20));   // 8 MB
  __bf16* vtb  = (__bf16*)(ws + ((size_t)32 << 20));   // 8 MB  [32][64][2048]
  __bf16* comb = (__bf16*)(ws + ((size_t)40 << 20));   // 8 MB  [4096][1024]

  cvt_kernel<<<4096, 256, 0, stream>>>(hs, hsb, 1048576);
  cvt_kernel<<<1024, 256, 0, stream>>>(wq, wqb, 262144);
  cvt_kernel<<<1024, 256, 0, stream>>>(wk, wkb, 262144);
  cvt_kernel<<<1024, 256, 0, stream>>>(wv, wvb, 262144);
  cvt_kernel<<<1024, 256, 0, stream>>>(wo, wob, 262144);

  gemm_bt<0><<<dim3(32, 8), 256, 0, stream>>>(hsb, wqb, qbuf, 4096, 1024);
  gemm_bt<0><<<dim3(32, 8), 256, 0, stream>>>(hsb, wkb, kbuf, 4096, 1024);
  gemm_bt<1><<<dim3(8, 32), 256, 0, stream>>>(wvb, hsb, vtb, 1024, 4096);

  attn_kernel<<<dim3(16, 32), 256, 0, stream>>>(qbuf, kbuf, vtb, memory, memnorm, beta, comb);

  gemm_bt<2><<<dim3(32, 8), 256, 0, stream>>>(comb, wob, out, 4096, 1024);
}

// Round 2
// 166.651 us; speedup vs baseline: 1.3177x; 1.3177x over previous
//
#include <hip/hip_runtime.h>
#include <stdint.h>

#define LOG2E 1.4426950408889634f

typedef __attribute__((ext_vector_type(8))) __bf16 bf16x8;
typedef __attribute__((ext_vector_type(4))) __bf16 bf16x4;
typedef __attribute__((ext_vector_type(4))) float f32x4;

__device__ inline void gll16(const void* g, void* l) {
  __builtin_amdgcn_global_load_lds(
      (const __attribute__((address_space(1))) void*)g,
      (__attribute__((address_space(3))) void*)l, 16, 0, 0);
}

// ---------------- fp32 -> bf16 conversion ----------------
__global__ __launch_bounds__(256) void cvt_kernel(const float* __restrict__ src,
                                                  __bf16* __restrict__ dst, int n4) {
  int i = blockIdx.x * 256 + threadIdx.x;
  if (i < n4) {
    float4 v = ((const float4*)src)[i];
    bf16x4 o;
    o[0] = (__bf16)v.x; o[1] = (__bf16)v.y; o[2] = (__bf16)v.z; o[3] = (__bf16)v.w;
    *(bf16x4*)&dst[(size_t)i * 4] = o;
  }
}

// ---------------- merged QKV projection GEMM ----------------
// 768 blocks. z = bid>>8:
//   z=0: qbuf = hsb @ wq^T   (M=4096, N=1024), write [b,h,s,d] bf16
//   z=1: kbuf = hsb @ wk^T   same shape/layout
//   z=2: vtb  = wv  @ hsb^T  (M=1024, N=4096), write [b,h,d,s] bf16 (V^T)
__global__ __launch_bounds__(256, 2) void qkv_gemm(
    const __bf16* __restrict__ hsb, const __bf16* __restrict__ wqb,
    const __bf16* __restrict__ wkb, const __bf16* __restrict__ wvb,
    __bf16* __restrict__ qbuf, __bf16* __restrict__ kbuf,
    __bf16* __restrict__ vtb) {
  constexpr int K = 1024;
  __shared__ __align__(16) __bf16 lta[128 * 32];
  __shared__ __align__(16) __bf16 ltb[128 * 32];
  const int bid = blockIdx.x;
  const int z = bid >> 8, r = bid & 255;
  const __bf16 *A, *Bt;
  int m0, n0;
  if (z < 2) {
    A = hsb; Bt = z ? wkb : wqb;
    m0 = (r & 31) * 128; n0 = (r >> 5) * 128;
  } else {
    A = wvb; Bt = hsb;
    m0 = (r & 7) * 128; n0 = (r >> 3) * 128;
  }
  const int tid = threadIdx.x;
  const int w = tid >> 6, l = tid & 63;
  const int lg = l >> 4, lr = l & 15;
  const int wm = (w >> 1) * 64, wn = (w & 1) * 64;
  f32x4 acc[4][4] = {};
  const int srow = w * 16 + (l >> 2);
  const int scol = (l & 3) * 8;
  const __bf16* ga = A + (size_t)(m0 + srow) * K + scol;
  const __bf16* gb = Bt + (size_t)(n0 + srow) * K + scol;
  __bf16* la = &lta[(size_t)w * 16 * 32];
  __bf16* lb = &ltb[(size_t)w * 16 * 32];
  for (int k0 = 0; k0 < K; k0 += 32) {
    __syncthreads();
    gll16(ga + k0, la);
    gll16(ga + 64 * K + k0, la + 64 * 32);
    gll16(gb + k0, lb);
    gll16(gb + 64 * K + k0, lb + 64 * 32);
    __syncthreads();
    bf16x8 af[4], bfr[4];
#pragma unroll
    for (int i = 0; i < 4; ++i) {
      af[i]  = *(const bf16x8*)&lta[(wm + i * 16 + lr) * 32 + lg * 8];
      bfr[i] = *(const bf16x8*)&ltb[(wn + i * 16 + lr) * 32 + lg * 8];
    }
#pragma unroll
    for (int i = 0; i < 4; ++i)
#pragma unroll
      for (int j = 0; j < 4; ++j)
        acc[i][j] = __builtin_amdgcn_mfma_f32_16x16x32_bf16(af[i], bfr[j], acc[i][j], 0, 0, 0);
  }
#pragma unroll
  for (int i = 0; i < 4; ++i)
#pragma unroll
    for (int j = 0; j < 4; ++j)
#pragma unroll
      for (int rr = 0; rr < 4; ++rr) {
        int gm = m0 + wm + i * 16 + lg * 4 + rr;
        int gn = n0 + wn + j * 16 + lr;
        float v = acc[i][j][rr];
        if (z < 2) {
          int bb = gm >> 11, s = gm & 2047, hh = gn >> 6, d = gn & 63;
          __bf16* dst = z ? kbuf : qbuf;
          dst[(((size_t)bb * 16 + hh) * 2048 + s) * 64 + d] = (__bf16)v;
        } else {
          int bb = gn >> 11, s = gn & 2047, hh = gm >> 6, d = gm & 63;
          vtb[(((size_t)bb * 16 + hh) * 64 + d) * 2048 + s] = (__bf16)v;
        }
      }
}

// ---------------- output GEMM: out = comb[M,K] * wo[N,K]^T, fp32 out ----------------
__global__ __launch_bounds__(256, 2) void gemm_out(const __bf16* __restrict__ A,
                                                   const __bf16* __restrict__ Bt,
                                                   float* __restrict__ C,
                                                   int M, int N) {
  constexpr int K = 1024;
  __shared__ __align__(16) __bf16 lta[128 * 32];
  __shared__ __align__(16) __bf16 ltb[128 * 32];
  const int tid = threadIdx.x;
  const int w = tid >> 6, l = tid & 63;
  const int lg = l >> 4, lr = l & 15;
  const int m0 = blockIdx.x * 128, n0 = blockIdx.y * 128;
  const int wm = (w >> 1) * 64, wn = (w & 1) * 64;
  f32x4 acc[4][4] = {};
  const int srow = w * 16 + (l >> 2);
  const int scol = (l & 3) * 8;
  const __bf16* ga = A + (size_t)(m0 + srow) * K + scol;
  const __bf16* gb = Bt + (size_t)(n0 + srow) * K + scol;
  __bf16* la = &lta[(size_t)w * 16 * 32];
  __bf16* lb = &ltb[(size_t)w * 16 * 32];
  for (int k0 = 0; k0 < K; k0 += 32) {
    __syncthreads();
    gll16(ga + k0, la);
    gll16(ga + 64 * K + k0, la + 64 * 32);
    gll16(gb + k0, lb);
    gll16(gb + 64 * K + k0, lb + 64 * 32);
    __syncthreads();
    bf16x8 af[4], bfr[4];
#pragma unroll
    for (int i = 0; i < 4; ++i) {
      af[i]  = *(const bf16x8*)&lta[(wm + i * 16 + lr) * 32 + lg * 8];
      bfr[i] = *(const bf16x8*)&ltb[(wn + i * 16 + lr) * 32 + lg * 8];
    }
#pragma unroll
    for (int i = 0; i < 4; ++i)
#pragma unroll
      for (int j = 0; j < 4; ++j)
        acc[i][j] = __builtin_amdgcn_mfma_f32_16x16x32_bf16(af[i], bfr[j], acc[i][j], 0, 0, 0);
  }
#pragma unroll
  for (int i = 0; i < 4; ++i)
#pragma unroll
    for (int j = 0; j < 4; ++j)
#pragma unroll
      for (int rr = 0; rr < 4; ++rr) {
        int gm = m0 + wm + i * 16 + lg * 4 + rr;
        int gn = n0 + wn + j * 16 + lr;
        C[(size_t)gm * N + gn] = acc[i][j][rr];
      }
}

// ---------------- attention + memory retrieval (balanced pairs) ----------------
// grid: (16 pairs, 32 bh), 256 threads (4 waves). Block p processes 64-row
// q-tiles t=p and t=31-p sequentially; each needs floor(t/2)+1 KV tiles of 128
// -> exactly 17 KV-iterations per block (perfect balance).
// Wave w owns q rows t*64 + w*16 .. +15.
#define KP 72    // K-tile padded cols   (d: 64 -> 72)
#define VP 136   // V^T-tile padded cols (sk: 128 -> 136)
#define PP 136   // P-tile padded cols
#define MTP 72   // memory^T padded cols

__global__ __launch_bounds__(256, 2) void attn_kernel(
    const __bf16* __restrict__ qb,    // [32][2048][64]
    const __bf16* __restrict__ kb,    // [32][2048][64]
    const __bf16* __restrict__ vtb,   // [32][64][2048]
    const float* __restrict__ memory, // [16][64][64]
    const float* __restrict__ memnorm,// [16][64]
    const float* __restrict__ beta,   // [16]
    __bf16* __restrict__ comb)        // [2][2048][16][64] == [4096][1024]
{
  __shared__ __align__(16) __bf16 kt[128 * KP];     // 18432 B
  __shared__ __align__(16) __bf16 vt[64 * VP];      // 17408 B
  __shared__ __align__(16) __bf16 pt[4 * 16 * PP];  // 17408 B (also hosts MT 80*72)

  const int tid = threadIdx.x;
  const int w = tid >> 6, l = tid & 63;
  const int lg = l >> 4, lr = l & 15;
  const int p = blockIdx.x, bh = blockIdx.y;
  const int hh = bh & 15, b = bh >> 4;

  const float gate = 1.f / (1.f + __builtin_amdgcn_exp2f(-beta[hh] * LOG2E));
  const float og = 1.f - gate;

  for (int half = 0; half < 2; ++half) {
    const int t = half ? (31 - p) : p;
    const int wq0 = t * 64 + w * 16;
    const int ntiles = (t >> 1) + 1;

    // ---- hoist Q fragments (A-layout: row=lr, k = kk*32 + lg*8 + j) ----
    bf16x8 qf[2];
#pragma unroll
    for (int kk = 0; kk < 2; ++kk)
      qf[kk] = *(const bf16x8*)(qb + ((size_t)bh * 2048 + wq0 + lr) * 64 + kk * 32 + lg * 8);

    // ---- flash state ----
    float mrun[4], lsum[4];
    f32x4 apv[4] = {};
#pragma unroll
    for (int r = 0; r < 4; ++r) { mrun[r] = -1e30f; lsum[r] = 0.f; }

    for (int kv = 0; kv < ntiles; ++kv) {
      const int kv0 = kv * 128;
      __syncthreads();
      // stage K tile [128][64] -> kt, V^T tile [64][128] -> vt
#pragma unroll
      for (int is = 0; is < 4; ++is) {
        int i16 = is * 256 + tid;                 // 0..1023
        int sk = i16 >> 3, d8 = (i16 & 7) * 8;
        *(bf16x8*)&kt[sk * KP + d8] =
            *(const bf16x8*)(kb + ((size_t)bh * 2048 + kv0 + sk) * 64 + d8);
        int d = i16 >> 4, sk8 = (i16 & 15) * 8;
        *(bf16x8*)&vt[d * VP + sk8] =
            *(const bf16x8*)(vtb + ((size_t)bh * 64 + d) * 2048 + kv0 + sk8);
      }
      __syncthreads();

      // ---- QK^T ----
      f32x4 sc[8] = {};
#pragma unroll
      for (int kk = 0; kk < 2; ++kk)
#pragma unroll
        for (int nf = 0; nf < 8; ++nf) {
          bf16x8 bb = *(const bf16x8*)&kt[(nf * 16 + lr) * KP + kk * 32 + lg * 8];
          sc[nf] = __builtin_amdgcn_mfma_f32_16x16x32_bf16(qf[kk], bb, sc[nf], 0, 0, 0);
        }

      // ---- scale + causal mask + row max ----
      const bool diag = (kv0 + 127 > wq0);
      float mnew[4] = {-1e30f, -1e30f, -1e30f, -1e30f};
#pragma unroll
      for (int nf = 0; nf < 8; ++nf)
#pragma unroll
        for (int r = 0; r < 4; ++r) {
          float v = sc[nf][r] * 0.125f;
          if (diag) {
            int row = wq0 + lg * 4 + r;
            int col = kv0 + nf * 16 + lr;
            if (col > row) v = -1e30f;
          }
          sc[nf][r] = v;
          mnew[r] = fmaxf(mnew[r], v);
        }
#pragma unroll
      for (int msk = 1; msk < 16; msk <<= 1)
#pragma unroll
        for (int r = 0; r < 4; ++r)
          mnew[r] = fmaxf(mnew[r], __shfl_xor(mnew[r], msk, 64));

      // ---- rescale running state ----
      float rs[4];
#pragma unroll
      for (int r = 0; r < 4; ++r) {
        float mo = mrun[r];
        float mn = fmaxf(mo, mnew[r]);
        mrun[r] = mn;
        float scl = __builtin_amdgcn_exp2f((mo - mn) * LOG2E);
        lsum[r] *= scl;
        rs[r] = 0.f;
#pragma unroll
        for (int nf = 0; nf < 4; ++nf) apv[nf][r] *= scl;
      }

      // ---- P = exp(S - m), row-sum, stash to LDS (D-layout -> A-layout) ----
#pragma unroll
      for (int nf = 0; nf < 8; ++nf)
#pragma unroll
        for (int r = 0; r < 4; ++r) {
          float pv = __builtin_amdgcn_exp2f((sc[nf][r] - mrun[r]) * LOG2E);
          rs[r] += pv;
          pt[(size_t)w * 16 * PP + (lg * 4 + r) * PP + nf * 16 + lr] = (__bf16)pv;
        }
#pragma unroll
      for (int msk = 1; msk < 16; msk <<= 1)
#pragma unroll
        for (int r = 0; r < 4; ++r)
          rs[r] += __shfl_xor(rs[r], msk, 64);
#pragma unroll
      for (int r = 0; r < 4; ++r) lsum[r] += rs[r];

      // ---- PV accumulate ----
#pragma unroll
      for (int kk = 0; kk < 4; ++kk) {
        bf16x8 pa = *(const bf16x8*)&pt[(size_t)w * 16 * PP + lr * PP + kk * 32 + lg * 8];
#pragma unroll
        for (int nf = 0; nf < 4; ++nf) {
          bf16x8 bb = *(const bf16x8*)&vt[(nf * 16 + lr) * VP + kk * 32 + lg * 8];
          apv[nf] = __builtin_amdgcn_mfma_f32_16x16x32_bf16(pa, bb, apv[nf], 0, 0, 0);
        }
      }
    }

    // ---- memory retrieval: sigma(Q) @ [M^T | mn replicated] via MFMA ----
    __syncthreads();  // all waves done with pt (P) reads
    __bf16* mt = pt;  // reuse pt region for memory^T [80][MTP]
    for (int i = tid; i < 64 * 64; i += 256) {
      int d = i >> 6, e = i & 63;
      mt[e * MTP + d] = (__bf16)memory[((size_t)hh * 64 + d) * 64 + e];
    }
    for (int i = tid; i < 16 * 64; i += 256) {
      int e = 64 + (i >> 6), d = i & 63;
      mt[e * MTP + d] = (__bf16)memnorm[hh * 64 + d];
    }
    __syncthreads();

    bf16x8 sf[2];
#pragma unroll
    for (int kk = 0; kk < 2; ++kk) {
      bf16x8 q = qf[kk], s;
#pragma unroll
      for (int j = 0; j < 8; ++j) {
        float x = (float)q[j];
        float sg = x > 0.f ? x + 1.f : __builtin_amdgcn_exp2f(x * LOG2E);
        s[j] = (__bf16)sg;
      }
      sf[kk] = s;
    }

    f32x4 am[5] = {};
#pragma unroll
    for (int kk = 0; kk < 2; ++kk)
#pragma unroll
      for (int nf = 0; nf < 5; ++nf) {
        bf16x8 bb = *(const bf16x8*)&mt[(nf * 16 + lr) * MTP + kk * 32 + lg * 8];
        am[nf] = __builtin_amdgcn_mfma_f32_16x16x32_bf16(sf[kk], bb, am[nf], 0, 0, 0);
      }

    // ---- combine + write ----
#pragma unroll
    for (int r = 0; r < 4; ++r) {
      int row = wq0 + lg * 4 + r;
      float linv = __builtin_amdgcn_rcpf(lsum[r]);
      float nrm = fmaxf(am[4][r], 1e-6f);
      float ninv = __builtin_amdgcn_rcpf(nrm);
      size_t base = ((size_t)b * 2048 + row) * 1024 + hh * 64;
#pragma unroll
      for (int nf = 0; nf < 4; ++nf) {
        float al = apv[nf][r] * linv;
        float amv = am[nf][r] * ninv;
        comb[base + nf * 16 + lr] = (__bf16)(gate * amv + og * al);
      }
    }
    __syncthreads();  // mt reads done before next half overwrites pt
  }
}

// ---------------- launch ----------------
extern "C" void kernel_launch(void* const* d_in, const int* in_sizes, int n_in,
                              void* d_out, int out_size, void* d_ws, size_t ws_size,
                              hipStream_t stream) {
  const float* hs      = (const float*)d_in[0];
  const float* wq      = (const float*)d_in[1];
  const float* wk      = (const float*)d_in[2];
  const float* wv      = (const float*)d_in[3];
  const float* wo      = (const float*)d_in[4];
  const float* beta    = (const float*)d_in[5];
  const float* memory  = (const float*)d_in[6];
  const float* memnorm = (const float*)d_in[7];
  float* out = (float*)d_out;

  char* ws = (char*)d_ws;
  __bf16* hsb  = (__bf16*)(ws);                        // 8 MB  [4096][1024]
  __bf16* wqb  = (__bf16*)(ws + ((size_t)8  << 20));   // 2 MB
  __bf16* wkb  = (__bf16*)(ws + ((size_t)10 << 20));   // 2 MB
  __bf16* wvb  = (__bf16*)(ws + ((size_t)12 << 20));   // 2 MB
  __bf16* wob  = (__bf16*)(ws + ((size_t)14 << 20));   // 2 MB
  __bf16* qbuf = (__bf16*)(ws + ((size_t)16 << 20));   // 8 MB  [32][2048][64]
  __bf16* kbuf = (__bf16*)(ws + ((size_t)24 << 20));   // 8 MB
  __bf16* vtb  = (__bf16*)(ws + ((size_t)32 << 20));   // 8 MB  [32][64][2048]
  __bf16* comb = (__bf16*)(ws + ((size_t)40 << 20));   // 8 MB  [4096][1024]

  cvt_kernel<<<4096, 256, 0, stream>>>(hs, hsb, 1048576);
  cvt_kernel<<<1024, 256, 0, stream>>>(wq, wqb, 262144);
  cvt_kernel<<<1024, 256, 0, stream>>>(wk, wkb, 262144);
  cvt_kernel<<<1024, 256, 0, stream>>>(wv, wvb, 262144);
  cvt_kernel<<<1024, 256, 0, stream>>>(wo, wob, 262144);

  qkv_gemm<<<768, 256, 0, stream>>>(hsb, wqb, wkb, wvb, qbuf, kbuf, vtb);

  attn_kernel<<<dim3(16, 32), 256, 0, stream>>>(qbuf, kbuf, vtb, memory, memnorm, beta, comb);

  gemm_out<<<dim3(32, 8), 256, 0, stream>>>(comb, wob, out, 4096, 1024);
}

// Round 3
// 114.613 us; speedup vs baseline: 1.9160x; 1.4540x over previous
//
#include <hip/hip_runtime.h>
#include <stdint.h>

#define LOG2E 1.4426950408889634f

typedef __attribute__((ext_vector_type(8))) __bf16 bf16x8;
typedef __attribute__((ext_vector_type(4))) __bf16 bf16x4;
typedef __attribute__((ext_vector_type(4))) float f32x4;

__device__ inline void gll16(const void* g, void* l) {
  __builtin_amdgcn_global_load_lds(
      (const __attribute__((address_space(1))) void*)g,
      (__attribute__((address_space(3))) void*)l, 16, 0, 0);
}

// ---------------- fp32 -> bf16 conversion (all 5 tensors, one launch) ----------------
__global__ __launch_bounds__(256) void cvt_all(
    const float* __restrict__ hs, const float* __restrict__ wq,
    const float* __restrict__ wk, const float* __restrict__ wv,
    const float* __restrict__ wo,
    __bf16* __restrict__ hsb, __bf16* __restrict__ wqb, __bf16* __restrict__ wkb,
    __bf16* __restrict__ wvb, __bf16* __restrict__ wob) {
  int bid = blockIdx.x;
  const float* s; __bf16* d; int i;
  if (bid < 4096) { s = hs; d = hsb; i = bid * 256 + threadIdx.x; }
  else {
    int seg = (bid - 4096) >> 10;
    i = ((bid - 4096) & 1023) * 256 + threadIdx.x;
    s = seg == 0 ? wq : seg == 1 ? wk : seg == 2 ? wv : wo;
    d = seg == 0 ? wqb : seg == 1 ? wkb : seg == 2 ? wvb : wob;
  }
  float4 v = ((const float4*)s)[i];
  bf16x4 o;
  o[0] = (__bf16)v.x; o[1] = (__bf16)v.y; o[2] = (__bf16)v.z; o[3] = (__bf16)v.w;
  *(bf16x4*)&d[(size_t)i * 4] = o;
}

// ---------------- merged QKV projection GEMM ----------------
// 768 blocks. z = bid>>8:
//   z=0: qbuf = hsb @ wq^T   write [b,h,s,d] bf16 (raw Q — memory term needs it)
//   z=1: kbuf = hsb @ wk^T   write [b,h,s,d] bf16, PRE-SCALED by 0.125*log2(e)
//   z=2: vtb  = wv  @ hsb^T  write [b,h,d,s] bf16 (V^T)
#define KSCALE 0.18033688011112042f  // HD^-0.5 * log2(e)
__global__ __launch_bounds__(256, 2) void qkv_gemm(
    const __bf16* __restrict__ hsb, const __bf16* __restrict__ wqb,
    const __bf16* __restrict__ wkb, const __bf16* __restrict__ wvb,
    __bf16* __restrict__ qbuf, __bf16* __restrict__ kbuf,
    __bf16* __restrict__ vtb) {
  constexpr int K = 1024;
  __shared__ __align__(16) __bf16 lta[128 * 32];
  __shared__ __align__(16) __bf16 ltb[128 * 32];
  const int bid = blockIdx.x;
  const int z = bid >> 8, r = bid & 255;
  const __bf16 *A, *Bt;
  int m0, n0;
  if (z < 2) {
    A = hsb; Bt = z ? wkb : wqb;
    m0 = (r & 31) * 128; n0 = (r >> 5) * 128;
  } else {
    A = wvb; Bt = hsb;
    m0 = (r & 7) * 128; n0 = (r >> 3) * 128;
  }
  const int tid = threadIdx.x;
  const int w = tid >> 6, l = tid & 63;
  const int lg = l >> 4, lr = l & 15;
  const int wm = (w >> 1) * 64, wn = (w & 1) * 64;
  f32x4 acc[4][4] = {};
  const int srow = w * 16 + (l >> 2);
  const int scol = (l & 3) * 8;
  const __bf16* ga = A + (size_t)(m0 + srow) * K + scol;
  const __bf16* gb = Bt + (size_t)(n0 + srow) * K + scol;
  __bf16* la = &lta[(size_t)w * 16 * 32];
  __bf16* lb = &ltb[(size_t)w * 16 * 32];
  for (int k0 = 0; k0 < K; k0 += 32) {
    __syncthreads();
    gll16(ga + k0, la);
    gll16(ga + 64 * K + k0, la + 64 * 32);
    gll16(gb + k0, lb);
    gll16(gb + 64 * K + k0, lb + 64 * 32);
    __syncthreads();
    bf16x8 af[4], bfr[4];
#pragma unroll
    for (int i = 0; i < 4; ++i) {
      af[i]  = *(const bf16x8*)&lta[(wm + i * 16 + lr) * 32 + lg * 8];
      bfr[i] = *(const bf16x8*)&ltb[(wn + i * 16 + lr) * 32 + lg * 8];
    }
#pragma unroll
    for (int i = 0; i < 4; ++i)
#pragma unroll
      for (int j = 0; j < 4; ++j)
        acc[i][j] = __builtin_amdgcn_mfma_f32_16x16x32_bf16(af[i], bfr[j], acc[i][j], 0, 0, 0);
  }
#pragma unroll
  for (int i = 0; i < 4; ++i)
#pragma unroll
    for (int j = 0; j < 4; ++j)
#pragma unroll
      for (int rr = 0; rr < 4; ++rr) {
        int gm = m0 + wm + i * 16 + lg * 4 + rr;
        int gn = n0 + wn + j * 16 + lr;
        float v = acc[i][j][rr];
        if (z < 2) {
          int bb = gm >> 11, s = gm & 2047, hh = gn >> 6, d = gn & 63;
          __bf16* dst = z ? kbuf : qbuf;
          if (z) v *= KSCALE;
          dst[(((size_t)bb * 16 + hh) * 2048 + s) * 64 + d] = (__bf16)v;
        } else {
          int bb = gn >> 11, s = gn & 2047, hh = gm >> 6, d = gm & 63;
          vtb[(((size_t)bb * 16 + hh) * 64 + d) * 2048 + s] = (__bf16)v;
        }
      }
}

// ---------------- output GEMM: out = comb[M,K] * wo[N,K]^T, fp32 out ----------------
__global__ __launch_bounds__(256, 2) void gemm_out(const __bf16* __restrict__ A,
                                                   const __bf16* __restrict__ Bt,
                                                   float* __restrict__ C,
                                                   int M, int N) {
  constexpr int K = 1024;
  __shared__ __align__(16) __bf16 lta[128 * 32];
  __shared__ __align__(16) __bf16 ltb[128 * 32];
  const int tid = threadIdx.x;
  const int w = tid >> 6, l = tid & 63;
  const int lg = l >> 4, lr = l & 15;
  const int m0 = blockIdx.x * 128, n0 = blockIdx.y * 128;
  const int wm = (w >> 1) * 64, wn = (w & 1) * 64;
  f32x4 acc[4][4] = {};
  const int srow = w * 16 + (l >> 2);
  const int scol = (l & 3) * 8;
  const __bf16* ga = A + (size_t)(m0 + srow) * K + scol;
  const __bf16* gb = Bt + (size_t)(n0 + srow) * K + scol;
  __bf16* la = &lta[(size_t)w * 16 * 32];
  __bf16* lb = &ltb[(size_t)w * 16 * 32];
  for (int k0 = 0; k0 < K; k0 += 32) {
    __syncthreads();
    gll16(ga + k0, la);
    gll16(ga + 64 * K + k0, la + 64 * 32);
    gll16(gb + k0, lb);
    gll16(gb + 64 * K + k0, lb + 64 * 32);
    __syncthreads();
    bf16x8 af[4], bfr[4];
#pragma unroll
    for (int i = 0; i < 4; ++i) {
      af[i]  = *(const bf16x8*)&lta[(wm + i * 16 + lr) * 32 + lg * 8];
      bfr[i] = *(const bf16x8*)&ltb[(wn + i * 16 + lr) * 32 + lg * 8];
    }
#pragma unroll
    for (int i = 0; i < 4; ++i)
#pragma unroll
      for (int j = 0; j < 4; ++j)
        acc[i][j] = __builtin_amdgcn_mfma_f32_16x16x32_bf16(af[i], bfr[j], acc[i][j], 0, 0, 0);
  }
#pragma unroll
  for (int i = 0; i < 4; ++i)
#pragma unroll
    for (int j = 0; j < 4; ++j)
#pragma unroll
      for (int rr = 0; rr < 4; ++rr) {
        int gm = m0 + wm + i * 16 + lg * 4 + rr;
        int gn = n0 + wn + j * 16 + lr;
        C[(size_t)gm * N + gn] = acc[i][j][rr];
      }
}

// ---------------- attention + memory retrieval ----------------
// grid: 1024 blocks, bx -> (t = 31 - (bx>>5), bh = bx&31); big-t blocks launch
// first for dynamic-refill balance. 4 waves; wave w owns q rows t*64+w*16..+15.
// Swapped QK^T: lane owns q-row = lr; softmax state is per-lane scalar.
// K is pre-scaled by 0.125*log2e, so softmax runs in exp2 domain.
#define KP 72    // K-tile padded cols
#define VP 136   // V^T-tile padded cols
#define PP 136   // P-tile padded cols (k dim 128 -> 136)
#define MTP 72   // memory^T padded cols
#define DEFER_THR 11.5f   // ~8 nats in log2 units

__global__ __launch_bounds__(256, 3) void attn_kernel(
    const __bf16* __restrict__ qb,    // [32][2048][64]
    const __bf16* __restrict__ kb,    // [32][2048][64] (pre-scaled)
    const __bf16* __restrict__ vtb,   // [32][64][2048]
    const float* __restrict__ memory, // [16][64][64]
    const float* __restrict__ memnorm,// [16][64]
    const float* __restrict__ beta,   // [16]
    __bf16* __restrict__ comb)        // [4096][1024]
{
  __shared__ __align__(16) __bf16 kt[128 * KP];     // 18432 B (reused as mt)
  __shared__ __align__(16) __bf16 vt[64 * VP];      // 17408 B
  __shared__ __align__(16) __bf16 pt[4 * 16 * PP];  // 17408 B  -> total 53248 B

  const int tid = threadIdx.x;
  const int w = tid >> 6, l = tid & 63;
  const int lg = l >> 4, lr = l & 15;
  const int bx = blockIdx.x;
  const int t = 31 - (bx >> 5);
  const int bh = bx & 31;
  const int hh = bh & 15, b = bh >> 4;
  const int wq0 = t * 64 + w * 16;
  const int ntiles = (t >> 1) + 1;

  // staging index math (per thread, fixed)
  const int s_sk = tid >> 3, s_d8 = (tid & 7) * 8;      // K tile coords (+32/is)
  const int s_d = tid >> 4, s_sk8 = (tid & 15) * 8;     // V^T tile coords (+16/is)
  const __bf16* kbase = kb + ((size_t)bh * 2048 + s_sk) * 64 + s_d8;
  const __bf16* vbase = vtb + ((size_t)bh * 64 + s_d) * 2048 + s_sk8;

  // ---- hoist Q fragments (per-lane: row/col = lr, k = kk*32 + lg*8 + j) ----
  bf16x8 qf[2];
#pragma unroll
  for (int kk = 0; kk < 2; ++kk)
    qf[kk] = *(const bf16x8*)(qb + ((size_t)bh * 2048 + wq0 + lr) * 64 + kk * 32 + lg * 8);

  // ---- prologue: load KV tile 0 into regs ----
  bf16x8 kst[4], vst[4];
#pragma unroll
  for (int is = 0; is < 4; ++is) {
    kst[is] = *(const bf16x8*)(kbase + (size_t)is * 32 * 64);
    vst[is] = *(const bf16x8*)(vbase + is * 16 * 2048);
  }

  // ---- flash state: per-lane, q-row = lr ----
  float mrun = -1e30f, lsum = 0.f;
  f32x4 apv[4] = {};

  for (int kv = 0; kv < ntiles; ++kv) {
    const int kv0 = kv * 128;
    __syncthreads();
#pragma unroll
    for (int is = 0; is < 4; ++is) {
      *(bf16x8*)&kt[(s_sk + is * 32) * KP + s_d8] = kst[is];
      *(bf16x8*)&vt[(s_d + is * 16) * VP + s_sk8] = vst[is];
    }
    __syncthreads();
    if (kv + 1 < ntiles) {
      const size_t off = (size_t)(kv + 1) * 128;
#pragma unroll
      for (int is = 0; is < 4; ++is) {
        kst[is] = *(const bf16x8*)(kbase + ((size_t)is * 32) * 64 + off * 64);
        vst[is] = *(const bf16x8*)(vbase + is * 16 * 2048 + off);
      }
    }

    // ---- QK^T swapped: sc[nf] holds S^T; lane: k = kv0+nf*16+lg*4+r, q = wq0+lr
    f32x4 sc[8] = {};
#pragma unroll
    for (int kk = 0; kk < 2; ++kk)
#pragma unroll
      for (int nf = 0; nf < 8; ++nf) {
        bf16x8 kf = *(const bf16x8*)&kt[(nf * 16 + lr) * KP + kk * 32 + lg * 8];
        sc[nf] = __builtin_amdgcn_mfma_f32_16x16x32_bf16(kf, qf[kk], sc[nf], 0, 0, 0);
      }

    // ---- causal mask + in-lane max + 2-shuffle reduce ----
    const int qrow = wq0 + lr;
    if (kv0 + 127 > wq0) {
#pragma unroll
      for (int nf = 0; nf < 8; ++nf)
#pragma unroll
        for (int r = 0; r < 4; ++r)
          if (kv0 + nf * 16 + lg * 4 + r > qrow) sc[nf][r] = -1e30f;
    }
    f32x4 m4 = sc[0];
#pragma unroll
    for (int nf = 1; nf < 8; ++nf)
#pragma unroll
      for (int r = 0; r < 4; ++r) m4[r] = fmaxf(m4[r], sc[nf][r]);
    float mx = fmaxf(fmaxf(m4[0], m4[1]), fmaxf(m4[2], m4[3]));
    mx = fmaxf(mx, __shfl_xor(mx, 16, 64));
    mx = fmaxf(mx, __shfl_xor(mx, 32, 64));

    // ---- defer-max rescale ----
    if (!__all(mx - mrun <= DEFER_THR)) {
      float mold = mrun;
      float mn = fmaxf(mold, mx);
      mrun = mn;
      float scl = __builtin_amdgcn_exp2f(mold - mn);
      lsum *= scl;
      float sclq[4];
#pragma unroll
      for (int r = 0; r < 4; ++r) sclq[r] = __shfl(scl, (lg << 2) | r, 16);
#pragma unroll
      for (int nf = 0; nf < 4; ++nf)
#pragma unroll
        for (int r = 0; r < 4; ++r) apv[nf][r] *= sclq[r];
    }

    // ---- P = exp2(S - m), in-lane sum, packed b64 store to pt ----
    float rs = 0.f;
#pragma unroll
    for (int nf = 0; nf < 8; ++nf) {
      bf16x4 pk;
#pragma unroll
      for (int r = 0; r < 4; ++r) {
        float pv = __builtin_amdgcn_exp2f(sc[nf][r] - mrun);
        rs += pv;
        pk[r] = (__bf16)pv;
      }
      *(bf16x4*)&pt[(w * 16 + lr) * PP + nf * 16 + lg * 4] = pk;
    }
    rs += __shfl_xor(rs, 16, 64);
    rs += __shfl_xor(rs, 32, 64);
    lsum += rs;

    // ---- PV accumulate: O[q=lg*4+r][d=nf*16+lr] ----
#pragma unroll
    for (int kk = 0; kk < 4; ++kk) {
      bf16x8 pa = *(const bf16x8*)&pt[(w * 16 + lr) * PP + kk * 32 + lg * 8];
#pragma unroll
      for (int nf = 0; nf < 4; ++nf) {
        bf16x8 vf = *(const bf16x8*)&vt[(nf * 16 + lr) * VP + kk * 32 + lg * 8];
        apv[nf] = __builtin_amdgcn_mfma_f32_16x16x32_bf16(pa, vf, apv[nf], 0, 0, 0);
      }
    }
  }

  // ---- memory retrieval: sigma(Q) @ [M^T | mn replicated] via MFMA ----
  __syncthreads();  // all waves done with kt (QK^T) reads
  __bf16* mt = kt;  // reuse kt region for memory^T [80][MTP]
  for (int i = tid; i < 64 * 64; i += 256) {
    int d = i >> 6, e = i & 63;
    mt[e * MTP + d] = (__bf16)memory[((size_t)hh * 64 + d) * 64 + e];
  }
  for (int i = tid; i < 16 * 64; i += 256) {
    int e = 64 + (i >> 6), d = i & 63;
    mt[e * MTP + d] = (__bf16)memnorm[hh * 64 + d];
  }
  __syncthreads();

  bf16x8 sf[2];
#pragma unroll
  for (int kk = 0; kk < 2; ++kk) {
    bf16x8 q = qf[kk], s;
#pragma unroll
    for (int j = 0; j < 8; ++j) {
      float x = (float)q[j];
      float sg = x > 0.f ? x + 1.f : __builtin_amdgcn_exp2f(x * LOG2E);
      s[j] = (__bf16)sg;
    }
    sf[kk] = s;
  }

  f32x4 am[5] = {};
#pragma unroll
  for (int kk = 0; kk < 2; ++kk)
#pragma unroll
    for (int nf = 0; nf < 5; ++nf) {
      bf16x8 bb = *(const bf16x8*)&mt[(nf * 16 + lr) * MTP + kk * 32 + lg * 8];
      am[nf] = __builtin_amdgcn_mfma_f32_16x16x32_bf16(sf[kk], bb, am[nf], 0, 0, 0);
    }

  // ---- combine + write ----
  const float gate = 1.f / (1.f + __builtin_amdgcn_exp2f(-beta[hh] * LOG2E));
  const float og = 1.f - gate;
  float lsq[4];
#pragma unroll
  for (int r = 0; r < 4; ++r) lsq[r] = __shfl(lsum, (lg << 2) | r, 16);
#pragma unroll
  for (int r = 0; r < 4; ++r) {
    int row = wq0 + lg * 4 + r;
    float linv = __builtin_amdgcn_rcpf(lsq[r]);
    float nrm = fmaxf(am[4][r], 1e-6f);
    float ninv = __builtin_amdgcn_rcpf(nrm);
    size_t base = ((size_t)b * 2048 + row) * 1024 + hh * 64;
#pragma unroll
    for (int nf = 0; nf < 4; ++nf) {
      float al = apv[nf][r] * linv;
      float amv = am[nf][r] * ninv;
      comb[base + nf * 16 + lr] = (__bf16)(gate * amv + og * al);
    }
  }
}

// ---------------- launch ----------------
extern "C" void kernel_launch(void* const* d_in, const int* in_sizes, int n_in,
                              void* d_out, int out_size, void* d_ws, size_t ws_size,
                              hipStream_t stream) {
  const float* hs      = (const float*)d_in[0];
  const float* wq      = (const float*)d_in[1];
  const float* wk      = (const float*)d_in[2];
  const float* wv      = (const float*)d_in[3];
  const float* wo      = (const float*)d_in[4];
  const float* beta    = (const float*)d_in[5];
  const float* memory  = (const float*)d_in[6];
  const float* memnorm = (const float*)d_in[7];
  float* out = (float*)d_out;

  char* ws = (char*)d_ws;
  __bf16* hsb  = (__bf16*)(ws);                        // 8 MB  [4096][1024]
  __bf16* wqb  = (__bf16*)(ws + ((size_t)8  << 20));   // 2 MB
  __bf16* wkb  = (__bf16*)(ws + ((size_t)10 << 20));   // 2 MB
  __bf16* wvb  = (__bf16*)(ws + ((size_t)12 << 20));   // 2 MB
  __bf16* wob  = (__bf16*)(ws + ((size_t)14 << 20));   // 2 MB
  __bf16* qbuf = (__bf16*)(ws + ((size_t)16 << 20));   // 8 MB  [32][2048][64]
  __bf16* kbuf = (__bf16*)(ws + ((size_t)24 << 20));   // 8 MB
  __bf16* vtb  = (__bf16*)(ws + ((size_t)32 << 20));   // 8 MB  [32][64][2048]
  __bf16* comb = (__bf16*)(ws + ((size_t)40 << 20));   // 8 MB  [4096][1024]

  cvt_all<<<8192, 256, 0, stream>>>(hs, wq, wk, wv, wo, hsb, wqb, wkb, wvb, wob);

  qkv_gemm<<<768, 256, 0, stream>>>(hsb, wqb, wkb, wvb, qbuf, kbuf, vtb);

  attn_kernel<<<1024, 256, 0, stream>>>(qbuf, kbuf, vtb, memory, memnorm, beta, comb);

  gemm_out<<<dim3(32, 8), 256, 0, stream>>>(comb, wob, out, 4096, 1024);
}

// Round 4
// 110.327 us; speedup vs baseline: 1.9904x; 1.0388x over previous
//
#include <hip/hip_runtime.h>
#include <stdint.h>

#define LOG2E 1.4426950408889634f

typedef __attribute__((ext_vector_type(8))) __bf16 bf16x8;
typedef __attribute__((ext_vector_type(4))) __bf16 bf16x4;
typedef __attribute__((ext_vector_type(4))) float f32x4;

__device__ inline void gll16(const void* g, void* l) {
  __builtin_amdgcn_global_load_lds(
      (const __attribute__((address_space(1))) void*)g,
      (__attribute__((address_space(3))) void*)l, 16, 0, 0);
}

// ---------------- fp32 -> bf16 conversion (all 5 tensors, one launch) ----------------
__global__ __launch_bounds__(256) void cvt_all(
    const float* __restrict__ hs, const float* __restrict__ wq,
    const float* __restrict__ wk, const float* __restrict__ wv,
    const float* __restrict__ wo,
    __bf16* __restrict__ hsb, __bf16* __restrict__ wqb, __bf16* __restrict__ wkb,
    __bf16* __restrict__ wvb, __bf16* __restrict__ wob) {
  int bid = blockIdx.x;
  const float* s; __bf16* d; int i;
  if (bid < 4096) { s = hs; d = hsb; i = bid * 256 + threadIdx.x; }
  else {
    int seg = (bid - 4096) >> 10;
    i = ((bid - 4096) & 1023) * 256 + threadIdx.x;
    s = seg == 0 ? wq : seg == 1 ? wk : seg == 2 ? wv : wo;
    d = seg == 0 ? wqb : seg == 1 ? wkb : seg == 2 ? wvb : wob;
  }
  float4 v = ((const float4*)s)[i];
  bf16x4 o;
  o[0] = (__bf16)v.x; o[1] = (__bf16)v.y; o[2] = (__bf16)v.z; o[3] = (__bf16)v.w;
  *(bf16x4*)&d[(size_t)i * 4] = o;
}

// ---------------- merged QKV projection GEMM ----------------
// 768 blocks = exactly 3 per CU. z = bid>>8:
//   z=0: qbuf = hsb @ wq^T   write [b,h,s,d] bf16 (raw Q — memory term needs it)
//   z=1: kbuf = hsb @ wk^T   write [b,h,s,d] bf16, PRE-SCALED by 0.125*log2(e)
//   z=2: vtb  = wv  @ hsb^T  write [b,h,d,s] bf16 (V^T)
#define KSCALE 0.18033688011112042f  // HD^-0.5 * log2(e)
__global__ __launch_bounds__(256, 3) void qkv_gemm(
    const __bf16* __restrict__ hsb, const __bf16* __restrict__ wqb,
    const __bf16* __restrict__ wkb, const __bf16* __restrict__ wvb,
    __bf16* __restrict__ qbuf, __bf16* __restrict__ kbuf,
    __bf16* __restrict__ vtb) {
  constexpr int K = 1024;
  __shared__ __align__(16) __bf16 lta[128 * 32];
  __shared__ __align__(16) __bf16 ltb[128 * 32];
  const int bid = blockIdx.x;
  const int z = bid >> 8, r = bid & 255;
  const __bf16 *A, *Bt;
  int m0, n0;
  if (z < 2) {
    A = hsb; Bt = z ? wkb : wqb;
    m0 = (r & 31) * 128; n0 = (r >> 5) * 128;
  } else {
    A = wvb; Bt = hsb;
    m0 = (r & 7) * 128; n0 = (r >> 3) * 128;
  }
  const int tid = threadIdx.x;
  const int w = tid >> 6, l = tid & 63;
  const int lg = l >> 4, lr = l & 15;
  const int wm = (w >> 1) * 64, wn = (w & 1) * 64;
  f32x4 acc[4][4] = {};
  const int srow = w * 16 + (l >> 2);
  const int scol = (l & 3) * 8;
  const __bf16* ga = A + (size_t)(m0 + srow) * K + scol;
  const __bf16* gb = Bt + (size_t)(n0 + srow) * K + scol;
  __bf16* la = &lta[(size_t)w * 16 * 32];
  __bf16* lb = &ltb[(size_t)w * 16 * 32];
  for (int k0 = 0; k0 < K; k0 += 32) {
    __syncthreads();
    gll16(ga + k0, la);
    gll16(ga + 64 * K + k0, la + 64 * 32);
    gll16(gb + k0, lb);
    gll16(gb + 64 * K + k0, lb + 64 * 32);
    __syncthreads();
    bf16x8 af[4], bfr[4];
#pragma unroll
    for (int i = 0; i < 4; ++i) {
      af[i]  = *(const bf16x8*)&lta[(wm + i * 16 + lr) * 32 + lg * 8];
      bfr[i] = *(const bf16x8*)&ltb[(wn + i * 16 + lr) * 32 + lg * 8];
    }
#pragma unroll
    for (int i = 0; i < 4; ++i)
#pragma unroll
      for (int j = 0; j < 4; ++j)
        acc[i][j] = __builtin_amdgcn_mfma_f32_16x16x32_bf16(af[i], bfr[j], acc[i][j], 0, 0, 0);
  }
#pragma unroll
  for (int i = 0; i < 4; ++i)
#pragma unroll
    for (int j = 0; j < 4; ++j)
#pragma unroll
      for (int rr = 0; rr < 4; ++rr) {
        int gm = m0 + wm + i * 16 + lg * 4 + rr;
        int gn = n0 + wn + j * 16 + lr;
        float v = acc[i][j][rr];
        if (z < 2) {
          int bb = gm >> 11, s = gm & 2047, hh = gn >> 6, d = gn & 63;
          __bf16* dst = z ? kbuf : qbuf;
          if (z) v *= KSCALE;
          dst[(((size_t)bb * 16 + hh) * 2048 + s) * 64 + d] = (__bf16)v;
        } else {
          int bb = gn >> 11, s = gn & 2047, hh = gm >> 6, d = gm & 63;
          vtb[(((size_t)bb * 16 + hh) * 64 + d) * 2048 + s] = (__bf16)v;
        }
      }
}

// ---------------- output GEMM: out = comb[M,K] * wo[N,K]^T, fp32 out ----------------
__global__ __launch_bounds__(256, 2) void gemm_out(const __bf16* __restrict__ A,
                                                   const __bf16* __restrict__ Bt,
                                                   float* __restrict__ C,
                                                   int M, int N) {
  constexpr int K = 1024;
  __shared__ __align__(16) __bf16 lta[128 * 32];
  __shared__ __align__(16) __bf16 ltb[128 * 32];
  const int tid = threadIdx.x;
  const int w = tid >> 6, l = tid & 63;
  const int lg = l >> 4, lr = l & 15;
  const int m0 = blockIdx.x * 128, n0 = blockIdx.y * 128;
  const int wm = (w >> 1) * 64, wn = (w & 1) * 64;
  f32x4 acc[4][4] = {};
  const int srow = w * 16 + (l >> 2);
  const int scol = (l & 3) * 8;
  const __bf16* ga = A + (size_t)(m0 + srow) * K + scol;
  const __bf16* gb = Bt + (size_t)(n0 + srow) * K + scol;
  __bf16* la = &lta[(size_t)w * 16 * 32];
  __bf16* lb = &ltb[(size_t)w * 16 * 32];
  for (int k0 = 0; k0 < K; k0 += 32) {
    __syncthreads();
    gll16(ga + k0, la);
    gll16(ga + 64 * K + k0, la + 64 * 32);
    gll16(gb + k0, lb);
    gll16(gb + 64 * K + k0, lb + 64 * 32);
    __syncthreads();
    bf16x8 af[4], bfr[4];
#pragma unroll
    for (int i = 0; i < 4; ++i) {
      af[i]  = *(const bf16x8*)&lta[(wm + i * 16 + lr) * 32 + lg * 8];
      bfr[i] = *(const bf16x8*)&ltb[(wn + i * 16 + lr) * 32 + lg * 8];
    }
#pragma unroll
    for (int i = 0; i < 4; ++i)
#pragma unroll
      for (int j = 0; j < 4; ++j)
        acc[i][j] = __builtin_amdgcn_mfma_f32_16x16x32_bf16(af[i], bfr[j], acc[i][j], 0, 0, 0);
  }
#pragma unroll
  for (int i = 0; i < 4; ++i)
#pragma unroll
    for (int j = 0; j < 4; ++j)
#pragma unroll
      for (int rr = 0; rr < 4; ++rr) {
        int gm = m0 + wm + i * 16 + lg * 4 + rr;
        int gn = n0 + wn + j * 16 + lr;
        C[(size_t)gm * N + gn] = acc[i][j][rr];
      }
}

// ---------------- attention + memory retrieval ----------------
// grid: 1024 blocks, bx -> (t = 31 - (bx>>5), bh = bx&31); big-t blocks first.
// 4 waves; wave w owns q rows t*64+w*16..+15. Swapped QK^T: lane owns q-row lr.
// K pre-scaled by 0.125*log2e -> softmax in exp2 domain.
// LDS tiles: power-of-2 row strides + XOR swizzle  elem ^= ((row&7)<<3)
//   (bank-group per 8-lane phase verified distinct for every access pattern).
#define MTP 72   // memory^T padded cols (epilogue only, one-shot)
#define DEFER_THR 11.5f   // ~8 nats in log2 units
#define SWZ(row, col) (((row) << 7) + ((col) ^ (((row) & 7) << 3)))   // stride 128
#define SWZK(row, col) (((row) << 6) + ((col) ^ (((row) & 7) << 3)))  // stride 64

__global__ __launch_bounds__(256, 3) void attn_kernel(
    const __bf16* __restrict__ qb,    // [32][2048][64]
    const __bf16* __restrict__ kb,    // [32][2048][64] (pre-scaled)
    const __bf16* __restrict__ vtb,   // [32][64][2048]
    const float* __restrict__ memory, // [16][64][64]
    const float* __restrict__ memnorm,// [16][64]
    const float* __restrict__ beta,   // [16]
    __bf16* __restrict__ comb)        // [4096][1024]
{
  __shared__ __align__(16) __bf16 kt[128 * 64];   // 16 KB (reused as mt)
  __shared__ __align__(16) __bf16 vt[64 * 128];   // 16 KB
  __shared__ __align__(16) __bf16 pt[64 * 128];   // 16 KB  -> total 48 KB

  const int tid = threadIdx.x;
  const int w = tid >> 6, l = tid & 63;
  const int lg = l >> 4, lr = l & 15;
  const int bx = blockIdx.x;
  const int t = 31 - (bx >> 5);
  const int bh = bx & 31;
  const int hh = bh & 15, b = bh >> 4;
  const int wq0 = t * 64 + w * 16;
  const int ntiles = (t >> 1) + 1;

  // staging index math (per thread, fixed)
  const int s_sk = tid >> 3, s_d8 = (tid & 7) * 8;      // K tile coords (+32/is)
  const int s_d = tid >> 4, s_sk8 = (tid & 15) * 8;     // V^T tile coords (+16/is)
  const __bf16* kbase = kb + ((size_t)bh * 2048 + s_sk) * 64 + s_d8;
  const __bf16* vbase = vtb + ((size_t)bh * 64 + s_d) * 2048 + s_sk8;

  // ---- hoist Q fragments (per-lane: row/col = lr, k = kk*32 + lg*8 + j) ----
  bf16x8 qf[2];
#pragma unroll
  for (int kk = 0; kk < 2; ++kk)
    qf[kk] = *(const bf16x8*)(qb + ((size_t)bh * 2048 + wq0 + lr) * 64 + kk * 32 + lg * 8);

  // ---- prologue: load KV tile 0 into regs ----
  bf16x8 kst[4], vst[4];
#pragma unroll
  for (int is = 0; is < 4; ++is) {
    kst[is] = *(const bf16x8*)(kbase + (size_t)is * 32 * 64);
    vst[is] = *(const bf16x8*)(vbase + is * 16 * 2048);
  }

  // ---- flash state: per-lane, q-row = lr ----
  float mrun = -1e30f, lsum = 0.f;
  f32x4 apv[4] = {};

  for (int kv = 0; kv < ntiles; ++kv) {
    const int kv0 = kv * 128;
    __syncthreads();
#pragma unroll
    for (int is = 0; is < 4; ++is) {
      *(bf16x8*)&kt[SWZK(s_sk + is * 32, s_d8)] = kst[is];
      *(bf16x8*)&vt[SWZ(s_d + is * 16, s_sk8)] = vst[is];
    }
    __syncthreads();
    if (kv + 1 < ntiles) {
      const size_t off = (size_t)(kv + 1) * 128;
#pragma unroll
      for (int is = 0; is < 4; ++is) {
        kst[is] = *(const bf16x8*)(kbase + ((size_t)is * 32) * 64 + off * 64);
        vst[is] = *(const bf16x8*)(vbase + is * 16 * 2048 + off);
      }
    }

    // ---- QK^T swapped: sc[nf] holds S^T; lane: k = kv0+nf*16+lg*4+r, q = wq0+lr
    f32x4 sc[8] = {};
#pragma unroll
    for (int kk = 0; kk < 2; ++kk)
#pragma unroll
      for (int nf = 0; nf < 8; ++nf) {
        bf16x8 kf = *(const bf16x8*)&kt[SWZK(nf * 16 + lr, kk * 32 + lg * 8)];
        sc[nf] = __builtin_amdgcn_mfma_f32_16x16x32_bf16(kf, qf[kk], sc[nf], 0, 0, 0);
      }

    // ---- causal mask (last tile only) + in-lane max + 2-shuffle reduce ----
    const int qrow = wq0 + lr;
    if (kv0 + 127 > wq0) {
#pragma unroll
      for (int nf = 0; nf < 8; ++nf)
#pragma unroll
        for (int r = 0; r < 4; ++r)
          if (kv0 + nf * 16 + lg * 4 + r > qrow) sc[nf][r] = -1e30f;
    }
    f32x4 m4 = sc[0];
#pragma unroll
    for (int nf = 1; nf < 8; ++nf)
#pragma unroll
      for (int r = 0; r < 4; ++r) m4[r] = fmaxf(m4[r], sc[nf][r]);
    float mx = fmaxf(fmaxf(m4[0], m4[1]), fmaxf(m4[2], m4[3]));
    mx = fmaxf(mx, __shfl_xor(mx, 16, 64));
    mx = fmaxf(mx, __shfl_xor(mx, 32, 64));

    // ---- defer-max rescale ----
    if (!__all(mx - mrun <= DEFER_THR)) {
      float mold = mrun;
      float mn = fmaxf(mold, mx);
      mrun = mn;
      float scl = __builtin_amdgcn_exp2f(mold - mn);
      lsum *= scl;
      float sclq[4];
#pragma unroll
      for (int r = 0; r < 4; ++r) sclq[r] = __shfl(scl, (lg << 2) | r, 16);
#pragma unroll
      for (int nf = 0; nf < 4; ++nf)
#pragma unroll
        for (int r = 0; r < 4; ++r) apv[nf][r] *= sclq[r];
    }

    // ---- P = exp2(S - m), in-lane sum, packed b64 store to pt ----
    float rs = 0.f;
#pragma unroll
    for (int nf = 0; nf < 8; ++nf) {
      bf16x4 pk;
#pragma unroll
      for (int r = 0; r < 4; ++r) {
        float pv = __builtin_amdgcn_exp2f(sc[nf][r] - mrun);
        rs += pv;
        pk[r] = (__bf16)pv;
      }
      *(bf16x4*)&pt[SWZ(w * 16 + lr, nf * 16 + lg * 4)] = pk;
    }
    rs += __shfl_xor(rs, 16, 64);
    rs += __shfl_xor(rs, 32, 64);
    lsum += rs;

    // ---- PV accumulate: O[q=lg*4+r][d=nf*16+lr] ----
#pragma unroll
    for (int kk = 0; kk < 4; ++kk) {
      bf16x8 pa = *(const bf16x8*)&pt[SWZ(w * 16 + lr, kk * 32 + lg * 8)];
#pragma unroll
      for (int nf = 0; nf < 4; ++nf) {
        bf16x8 vf = *(const bf16x8*)&vt[SWZ(nf * 16 + lr, kk * 32 + lg * 8)];
        apv[nf] = __builtin_amdgcn_mfma_f32_16x16x32_bf16(pa, vf, apv[nf], 0, 0, 0);
      }
    }
  }

  // ---- memory retrieval: sigma(Q) @ [M^T | mn replicated] via MFMA ----
  __syncthreads();  // all waves done with kt (QK^T) reads
  __bf16* mt = kt;  // reuse kt region for memory^T [80][MTP]
  for (int i = tid; i < 64 * 64; i += 256) {
    int d = i >> 6, e = i & 63;
    mt[e * MTP + d] = (__bf16)memory[((size_t)hh * 64 + d) * 64 + e];
  }
  for (int i = tid; i < 16 * 64; i += 256) {
    int e = 64 + (i >> 6), d = i & 63;
    mt[e * MTP + d] = (__bf16)memnorm[hh * 64 + d];
  }
  __syncthreads();

  bf16x8 sf[2];
#pragma unroll
  for (int kk = 0; kk < 2; ++kk) {
    bf16x8 q = qf[kk], s;
#pragma unroll
    for (int j = 0; j < 8; ++j) {
      float x = (float)q[j];
      float sg = x > 0.f ? x + 1.f : __builtin_amdgcn_exp2f(x * LOG2E);
      s[j] = (__bf16)sg;
    }
    sf[kk] = s;
  }

  f32x4 am[5] = {};
#pragma unroll
  for (int kk = 0; kk < 2; ++kk)
#pragma unroll
    for (int nf = 0; nf < 5; ++nf) {
      bf16x8 bb = *(const bf16x8*)&mt[(nf * 16 + lr) * MTP + kk * 32 + lg * 8];
      am[nf] = __builtin_amdgcn_mfma_f32_16x16x32_bf16(sf[kk], bb, am[nf], 0, 0, 0);
    }

  // ---- combine + write ----
  const float gate = 1.f / (1.f + __builtin_amdgcn_exp2f(-beta[hh] * LOG2E));
  const float og = 1.f - gate;
  float lsq[4];
#pragma unroll
  for (int r = 0; r < 4; ++r) lsq[r] = __shfl(lsum, (lg << 2) | r, 16);
#pragma unroll
  for (int r = 0; r < 4; ++r) {
    int row = wq0 + lg * 4 + r;
    float linv = __builtin_amdgcn_rcpf(lsq[r]);
    float nrm = fmaxf(am[4][r], 1e-6f);
    float ninv = __builtin_amdgcn_rcpf(nrm);
    size_t base = ((size_t)b * 2048 + row) * 1024 + hh * 64;
#pragma unroll
    for (int nf = 0; nf < 4; ++nf) {
      float al = apv[nf][r] * linv;
      float amv = am[nf][r] * ninv;
      comb[base + nf * 16 + lr] = (__bf16)(gate * amv + og * al);
    }
  }
}

// ---------------- launch ----------------
extern "C" void kernel_launch(void* const* d_in, const int* in_sizes, int n_in,
                              void* d_out, int out_size, void* d_ws, size_t ws_size,
                              hipStream_t stream) {
  const float* hs      = (const float*)d_in[0];
  const float* wq      = (const float*)d_in[1];
  const float* wk      = (const float*)d_in[2];
  const float* wv      = (const float*)d_in[3];
  const float* wo      = (const float*)d_in[4];
  const float* beta    = (const float*)d_in[5];
  const float* memory  = (const float*)d_in[6];
  const float* memnorm = (const float*)d_in[7];
  float* out = (float*)d_out;

  char* ws = (char*)d_ws;
  __bf16* hsb  = (__bf16*)(ws);                        // 8 MB  [4096][1024]
  __bf16* wqb  = (__bf16*)(ws + ((size_t)8  << 20));   // 2 MB
  __bf16* wkb  = (__bf16*)(ws + ((size_t)10 << 20));   // 2 MB
  __bf16* wvb  = (__bf16*)(ws + ((size_t)12 << 20));   // 2 MB
  __bf16* wob  = (__bf16*)(ws + ((size_t)14 << 20));   // 2 MB
  __bf16* qbuf = (__bf16*)(ws + ((size_t)16 << 20));   // 8 MB  [32][2048][64]
  __bf16* kbuf = (__bf16*)(ws + ((size_t)24 << 20));   // 8 MB
  __bf16* vtb  = (__bf16*)(ws + ((size_t)32 << 20));   // 8 MB  [32][64][2048]
  __bf16* comb = (__bf16*)(ws + ((size_t)40 << 20));   // 8 MB  [4096][1024]

  cvt_all<<<8192, 256, 0, stream>>>(hs, wq, wk, wv, wo, hsb, wqb, wkb, wvb, wob);

  qkv_gemm<<<768, 256, 0, stream>>>(hsb, wqb, wkb, wvb, qbuf, kbuf, vtb);

  attn_kernel<<<1024, 256, 0, stream>>>(qbuf, kbuf, vtb, memory, memnorm, beta, comb);

  gemm_out<<<dim3(32, 8), 256, 0, stream>>>(comb, wob, out, 4096, 1024);
}